// Round 4
// baseline (232.779 us; speedup 1.0000x reference)
//
#include <hip/hip_runtime.h>

// LightGCN propagation on MI355X (gfx950).
//   h_{k+1}[r,:] = sum_{e: row[e]==r} val[e] * h_k[col[e],:]   D=32
//   out = (x + h1 + h2 + h3) / 4
//
// Round 13: R12 = 195.3 us, all kernels now below the 43.5 us harness
// fills. Remaining budget ~120 us is the 3 spmm dispatches, which R10
// counters showed fetch 64 MB/layer vs a 6.4 MB gather table (random col
// order -> whole table live -> 4 MB/XCD L2 thrashes; misses served by L3
// at 200+ cy). Fix: col-sort each row's adjacency during bucket_sort --
// the bucket (<=~2300 edges) is staged in LDS, 128 threads insertion-sort
// their own row segments (avg deg 16), write-back coalesced. In spmm,
// wave-iteration k then touches col-quantile ~k/deg: all resident waves
// sweep a moving band of the table that fits per-XCD L2. Predicted FETCH
// 64 -> ~20 MB/layer. Buckets >3072 (statistically impossible, +22 sigma)
// fall back to the old unsorted path.

#define NN 100000
#define NE 1600000
#define DD 32
#define CHUNK 4096
#define NCHUNK ((NE + CHUNK - 1) / CHUNK)   // 391
#define BROWS 128
#define NBKT ((NN + BROWS - 1) / BROWS)     // 782
#define LDSE 3072                           // LDS staging cap in bucket_sort

__device__ __forceinline__ unsigned f2bf(float f) {
    unsigned u = __float_as_uint(f);
    return (u + 0x7fffu + ((u >> 16) & 1u)) >> 16;   // RNE
}

// ---- pass 1: per-chunk bucket histogram matrix H[c][b] (coalesced) -------

__global__ __launch_bounds__(1024) void hist_kernel(
    const int* __restrict__ row, int* __restrict__ H)
{
    __shared__ int cnt[NBKT];
    const int tid = threadIdx.x;
    const int start = blockIdx.x * CHUNK;
    const int n = min(CHUNK, NE - start);
    for (int k = tid; k < NBKT; k += 1024) cnt[k] = 0;
    __syncthreads();
    const int j = tid * 4;                       // 4 edges per thread
    if (j + 3 < n) {
        int4 r4 = *(const int4*)(row + start + j);
        atomicAdd(&cnt[r4.x >> 7], 1);
        atomicAdd(&cnt[r4.y >> 7], 1);
        atomicAdd(&cnt[r4.z >> 7], 1);
        atomicAdd(&cnt[r4.w >> 7], 1);
    } else {
        for (int k = j; k < n; k++) atomicAdd(&cnt[row[start + k] >> 7], 1);
    }
    __syncthreads();
    int* Hrow = H + (size_t)blockIdx.x * NBKT;
    for (int k = tid; k < NBKT; k += 1024) Hrow[k] = cnt[k];   // coalesced
}

// ---- pass 2a: wave-parallel per-bucket scan over chunks ------------------

__global__ __launch_bounds__(1024) void scan_tr_kernel(
    const int* __restrict__ H, int* __restrict__ Pt, int* __restrict__ tot)
{
    const int b = blockIdx.x * 16 + (threadIdx.x >> 6);
    if (b >= NBKT) return;
    const int lane = threadIdx.x & 63;
    int run = 0;
    #pragma unroll
    for (int c0 = 0; c0 < NCHUNK; c0 += 64) {
        int c = c0 + lane;
        int v = (c < NCHUNK) ? H[(size_t)c * NBKT + b] : 0;
        int x = v;
        #pragma unroll
        for (int off = 1; off < 64; off <<= 1) {
            int y = __shfl_up(x, off, 64);
            if (lane >= off) x += y;
        }
        if (c < NCHUNK) Pt[(size_t)b * NCHUNK + c] = run + x - v;  // exclusive
        run += __shfl(x, 63, 64);                 // wave total
    }
    if (lane == 0) tot[b] = run;
}

// ---- pass 2b: exclusive scan of 782 bucket totals ------------------------

__global__ __launch_bounds__(1024) void scan_buckets_kernel(
    const int* __restrict__ tot, int* __restrict__ bucketbase,
    int* __restrict__ row_ptr)
{
    const int tid = threadIdx.x;
    int v = (tid < NBKT) ? tot[tid] : 0;
    int lane = tid & 63, w = tid >> 6;          // 16 waves
    int x = v;
    #pragma unroll
    for (int off = 1; off < 64; off <<= 1) {
        int y = __shfl_up(x, off, 64);
        if (lane >= off) x += y;
    }
    __shared__ int wt[16];
    if (lane == 63) wt[w] = x;
    __syncthreads();
    if (w == 0 && lane < 16) {
        int y = wt[lane];
        #pragma unroll
        for (int off = 1; off < 16; off <<= 1) {
            int z = __shfl_up(y, off, 16);
            if ((lane & 15) >= off) y += z;
        }
        wt[lane] = y;                            // inclusive wave totals
    }
    __syncthreads();
    int wo = (w > 0) ? wt[w - 1] : 0;
    int excl = x + wo - v;
    if (tid < NBKT) bucketbase[tid] = excl;
    if (tid == NBKT) { bucketbase[NBKT] = NE; row_ptr[NN] = NE; }
}

// ---- pass 3: multisplit scatter, deterministic dest, LDS-staged stores ---
// record: ((row & 127) << 17) | col   (col < 2^17), val bits in .y

__global__ __launch_bounds__(1024) void scatter_kernel(
    const int* __restrict__ row, const int* __restrict__ col,
    const float* __restrict__ val, const int* __restrict__ bucketbase,
    const int* __restrict__ Pt, int2* __restrict__ tmp)
{
    __shared__ int cnt[NBKT];      // 3.1 KB
    __shared__ int lbase[NBKT];    // 3.1 KB  chunk-local exclusive scan
    __shared__ int gofs[NBKT];     // 3.1 KB  global base per bucket
    __shared__ int wt[16];
    __shared__ int2 recs[CHUNK];   // 32 KB   records in bucket order
    __shared__ int dest[CHUNK];    // 16 KB   global dst per sorted position
    const int tid = threadIdx.x;
    const int start = blockIdx.x * CHUNK;
    const int n = min(CHUNK, NE - start);
    for (int k = tid; k < NBKT; k += 1024) cnt[k] = 0;
    __syncthreads();

    int rrow[CHUNK / 1024], rcol[CHUNK / 1024], rank[CHUNK / 1024];
    float rval[CHUNK / 1024];
    #pragma unroll
    for (int k = 0; k < CHUNK / 1024; k++) {
        int j = k * 1024 + tid;
        if (j < n) {
            int r = row[start + j];
            rrow[k] = r;
            rcol[k] = col[start + j];
            rval[k] = val[start + j];
            rank[k] = atomicAdd(&cnt[r >> 7], 1);
        } else {
            rrow[k] = -1;
        }
    }
    __syncthreads();

    // block-level exclusive scan of cnt -> lbase; deterministic gofs
    int v = (tid < NBKT) ? cnt[tid] : 0;
    {
        int lane = tid & 63, w = tid >> 6;
        int x = v;
        #pragma unroll
        for (int off = 1; off < 64; off <<= 1) {
            int y = __shfl_up(x, off, 64);
            if (lane >= off) x += y;
        }
        if (lane == 63) wt[w] = x;
        __syncthreads();
        if (w == 0 && lane < 16) {
            int y = wt[lane];
            #pragma unroll
            for (int off = 1; off < 16; off <<= 1) {
                int z = __shfl_up(y, off, 16);
                if ((lane & 15) >= off) y += z;
            }
            wt[lane] = y;
        }
        __syncthreads();
        int excl = x + ((w > 0) ? wt[w - 1] : 0) - v;
        if (tid < NBKT) {
            lbase[tid] = excl;
            gofs[tid] = bucketbase[tid] + Pt[(size_t)tid * NCHUNK + blockIdx.x];
        }
    }
    __syncthreads();

    #pragma unroll
    for (int k = 0; k < CHUNK / 1024; k++) {
        if (rrow[k] >= 0) {
            int b = rrow[k] >> 7;
            int p = lbase[b] + rank[k];
            recs[p] = make_int2(((rrow[k] & 127) << 17) | rcol[k],
                                __float_as_int(rval[k]));
            dest[p] = gofs[b] + rank[k];
        }
    }
    __syncthreads();

    for (int p = tid; p < n; p += 1024)        // run-contiguous stores
        tmp[dest[p]] = recs[p];
}

// ---- pass 4: per-bucket row sort + per-row COL sort -> CSR edges ---------
// Staged in LDS; 128 threads insertion-sort their own row segments so the
// spmm consumes col-ascending adjacency (moving-band L2 locality).

__global__ __launch_bounds__(512) void bucket_sort_kernel(
    const int* __restrict__ bucketbase, const int2* __restrict__ tmp,
    int* __restrict__ row_ptr, int2* __restrict__ edges)
{
    __shared__ int cnt[BROWS];
    __shared__ int cur[BROWS];
    __shared__ int seg0[BROWS];
    __shared__ int wt2[2];
    __shared__ int2 ed[LDSE];      // 24 KB staging
    const int tid = threadIdx.x;
    const int b   = blockIdx.x;
    const int s   = bucketbase[b];
    const int e   = bucketbase[b + 1];
    const int tot = e - s;

    if (tid < BROWS) cnt[tid] = 0;
    __syncthreads();

    int2 rc[6];
    #pragma unroll
    for (int k = 0; k < 6; k++) {
        int j = s + k * 512 + tid;
        rc[k] = (j < e && j < s + LDSE) ? tmp[j] : make_int2(-1, 0);
        if (rc[k].x >= 0) atomicAdd(&cnt[rc[k].x >> 17], 1);
    }
    if (tot > LDSE)                                        // fallback count
        for (int j = s + LDSE + tid; j < e; j += 512)
            atomicAdd(&cnt[tmp[j].x >> 17], 1);
    __syncthreads();

    int v = 0, x = 0;
    if (tid < BROWS) {
        v = cnt[tid];
        int lane = tid & 63;
        x = v;
        #pragma unroll
        for (int off = 1; off < 64; off <<= 1) {
            int y = __shfl_up(x, off, 64);
            if (lane >= off) x += y;
        }
        if (lane == 63) wt2[tid >> 6] = x;
    }
    __syncthreads();
    if (tid < BROWS) {
        int excl = x + ((tid >> 6) ? wt2[0] : 0) - v;
        cur[tid] = excl;
        seg0[tid] = excl;
        int r = b * BROWS + tid;
        if (r < NN) row_ptr[r] = s + excl;
    }
    __syncthreads();

    if (tot <= LDSE) {
        // place into LDS at row-grouped positions
        #pragma unroll
        for (int k = 0; k < 6; k++) {
            if (rc[k].x >= 0) {
                int pos = atomicAdd(&cur[rc[k].x >> 17], 1);
                ed[pos] = make_int2(rc[k].x & 0x1FFFF, rc[k].y);
            }
        }
        __syncthreads();
        // per-row insertion sort by col (thread r owns its segment)
        if (tid < BROWS) {
            int s0 = seg0[tid], s1 = cur[tid];
            for (int a = s0 + 1; a < s1; a++) {
                int2 key = ed[a];
                int p = a - 1;
                while (p >= s0 && ed[p].x > key.x) { ed[p + 1] = ed[p]; p--; }
                ed[p + 1] = key;
            }
        }
        __syncthreads();
        for (int k = tid; k < tot; k += 512)     // coalesced write-back
            edges[s + k] = ed[k];
    } else {
        // unsorted fallback (statistically unreachable: bucket > 3072)
        #pragma unroll
        for (int k = 0; k < 6; k++) {
            if (rc[k].x >= 0) {
                int pos = s + atomicAdd(&cur[rc[k].x >> 17], 1);
                edges[pos] = make_int2(rc[k].x & 0x1FFFF, rc[k].y);
            }
        }
        for (int j = s + LDSE + tid; j < e; j += 512) {
            int2 rec = tmp[j];
            int pos = s + atomicAdd(&cur[rec.x >> 17], 1);
            edges[pos] = make_int2(rec.x & 0x1FFFF, rec.y);
        }
    }
}

// ---- x -> bf16 table (feat 2k in low half, 2k+1 in high half) ------------

__global__ __launch_bounds__(256) void cvt_kernel(
    const float2* __restrict__ xin2, unsigned* __restrict__ hb)
{
    int j = blockIdx.x * 256 + threadIdx.x;      // word index, NN*DD/2 words
    if (j >= NN * DD / 2) return;
    float2 f = xin2[j];
    hb[j] = f2bf(f.x) | (f2bf(f.y) << 16);
}

// ---- SpMM: 4-lane group per row, bf16 gather (64 B row = 1 line) ---------
// Lane t in [0,4) owns feats [8t, 8t+8) = one uint4 of the bf16 row.
// Adjacency is col-sorted per row: resident waves sweep a moving band of
// the table -> band fits per-XCD L2. 8 gathers in flight.
// MODE 0: houtb = bf16(A x)  ; out  = x + A x
// MODE 1: houtb = bf16(A h)  ; out += A h
// MODE 2: out = (out + A h) * 0.25

template <int MODE>
__global__ __launch_bounds__(256) void spmm_kernel(
    const int* __restrict__ row_ptr, const int2* __restrict__ edges,
    const uint4* __restrict__ hb4,               // bf16 table, 4 uint4/row
    uint4* __restrict__ houtb4,                  // next bf16 table
    const float4* __restrict__ xin4, float4* __restrict__ out4)
{
    const int g = blockIdx.x * 64 + (threadIdx.x >> 2);   // row
    if (g >= NN) return;
    const int t = threadIdx.x & 3;
    const int s = row_ptr[g];
    const int e = row_ptr[g + 1];

    float acc[8] = {0.f, 0.f, 0.f, 0.f, 0.f, 0.f, 0.f, 0.f};

#define ACC8(W, V)                                                         \
    do {                                                                   \
        acc[0] += (V) * __uint_as_float((W).x << 16);                      \
        acc[1] += (V) * __uint_as_float((W).x & 0xffff0000u);              \
        acc[2] += (V) * __uint_as_float((W).y << 16);                      \
        acc[3] += (V) * __uint_as_float((W).y & 0xffff0000u);              \
        acc[4] += (V) * __uint_as_float((W).z << 16);                      \
        acc[5] += (V) * __uint_as_float((W).z & 0xffff0000u);              \
        acc[6] += (V) * __uint_as_float((W).w << 16);                      \
        acc[7] += (V) * __uint_as_float((W).w & 0xffff0000u);              \
    } while (0)

    int i = s;
    for (; i + 8 <= e; i += 8) {                 // 8 gathers in flight
        int2 a0 = edges[i];
        int2 a1 = edges[i + 1];
        int2 a2 = edges[i + 2];
        int2 a3 = edges[i + 3];
        int2 a4 = edges[i + 4];
        int2 a5 = edges[i + 5];
        int2 a6 = edges[i + 6];
        int2 a7 = edges[i + 7];
        uint4 w0 = hb4[a0.x * 4 + t];
        uint4 w1 = hb4[a1.x * 4 + t];
        uint4 w2 = hb4[a2.x * 4 + t];
        uint4 w3 = hb4[a3.x * 4 + t];
        uint4 w4 = hb4[a4.x * 4 + t];
        uint4 w5 = hb4[a5.x * 4 + t];
        uint4 w6 = hb4[a6.x * 4 + t];
        uint4 w7 = hb4[a7.x * 4 + t];
        ACC8(w0, __int_as_float(a0.y)); ACC8(w1, __int_as_float(a1.y));
        ACC8(w2, __int_as_float(a2.y)); ACC8(w3, __int_as_float(a3.y));
        ACC8(w4, __int_as_float(a4.y)); ACC8(w5, __int_as_float(a5.y));
        ACC8(w6, __int_as_float(a6.y)); ACC8(w7, __int_as_float(a7.y));
    }
    for (; i + 4 <= e; i += 4) {
        int2 a0 = edges[i];
        int2 a1 = edges[i + 1];
        int2 a2 = edges[i + 2];
        int2 a3 = edges[i + 3];
        uint4 w0 = hb4[a0.x * 4 + t];
        uint4 w1 = hb4[a1.x * 4 + t];
        uint4 w2 = hb4[a2.x * 4 + t];
        uint4 w3 = hb4[a3.x * 4 + t];
        ACC8(w0, __int_as_float(a0.y)); ACC8(w1, __int_as_float(a1.y));
        ACC8(w2, __int_as_float(a2.y)); ACC8(w3, __int_as_float(a3.y));
    }
    for (; i < e; ++i) {
        int2 a0 = edges[i];
        uint4 w0 = hb4[a0.x * 4 + t];
        ACC8(w0, __int_as_float(a0.y));
    }
#undef ACC8

    // epilogue: lane owns feats [8t, 8t+8)
    if (MODE == 0 || MODE == 1) {
        uint4 p;
        p.x = f2bf(acc[0]) | (f2bf(acc[1]) << 16);
        p.y = f2bf(acc[2]) | (f2bf(acc[3]) << 16);
        p.z = f2bf(acc[4]) | (f2bf(acc[5]) << 16);
        p.w = f2bf(acc[6]) | (f2bf(acc[7]) << 16);
        houtb4[g * 4 + t] = p;
    }
    const int o = g * 8 + t * 2;                 // two float4s per lane
    float4 lo, hi;
    if (MODE == 0) {
        float4 x0 = xin4[o], x1 = xin4[o + 1];
        lo = make_float4(x0.x + acc[0], x0.y + acc[1], x0.z + acc[2], x0.w + acc[3]);
        hi = make_float4(x1.x + acc[4], x1.y + acc[5], x1.z + acc[6], x1.w + acc[7]);
    } else if (MODE == 1) {
        float4 o0 = out4[o], o1 = out4[o + 1];
        lo = make_float4(o0.x + acc[0], o0.y + acc[1], o0.z + acc[2], o0.w + acc[3]);
        hi = make_float4(o1.x + acc[4], o1.y + acc[5], o1.z + acc[6], o1.w + acc[7]);
    } else {
        float4 o0 = out4[o], o1 = out4[o + 1];
        lo = make_float4((o0.x + acc[0]) * 0.25f, (o0.y + acc[1]) * 0.25f,
                         (o0.z + acc[2]) * 0.25f, (o0.w + acc[3]) * 0.25f);
        hi = make_float4((o1.x + acc[4]) * 0.25f, (o1.y + acc[5]) * 0.25f,
                         (o1.z + acc[6]) * 0.25f, (o1.w + acc[7]) * 0.25f);
    }
    out4[o] = lo;
    out4[o + 1] = hi;
}

// ---- launch ---------------------------------------------------------------

extern "C" void kernel_launch(void* const* d_in, const int* in_sizes, int n_in,
                              void* d_out, int out_size, void* d_ws, size_t ws_size,
                              hipStream_t stream) {
    const int*   edge_row = (const int*)d_in[0];
    const int*   edge_col = (const int*)d_in[1];
    const float* edge_val = (const float*)d_in[2];
    const float* x        = (const float*)d_in[3];
    float* out = (float*)d_out;

    char* ws = (char*)d_ws;
    int*  H          = (int*)ws;   ws += (((size_t)NCHUNK * NBKT * 4) + 511) & ~511ull; // 1.22 MB
    int*  Pt         = (int*)ws;   ws += (((size_t)NBKT * NCHUNK * 4) + 511) & ~511ull; // 1.22 MB
    int*  tot        = (int*)ws;   ws += 4096;
    int*  bucketbase = (int*)ws;   ws += 4096;
    int*  row_ptr    = (int*)ws;   ws += ((size_t)(NN + 1) * 4 + 511) & ~511ull;
    int2* tmp        = (int2*)ws;  ws += (size_t)NE * 8 + 64;   // 12.8 MB
    int2* edges      = (int2*)ws;  ws += (size_t)NE * 8 + 64;   // 12.8 MB
    unsigned* hb0    = (unsigned*)ws;  ws += (size_t)NN * DD * 2;  // 6.4 MB bf16
    unsigned* hb1    = (unsigned*)ws;  ws += (size_t)NN * DD * 2;  // 6.4 MB bf16

    hist_kernel        <<<NCHUNK, 1024, 0, stream>>>(edge_row, H);
    scan_tr_kernel     <<<(NBKT + 15) / 16, 1024, 0, stream>>>(H, Pt, tot);
    scan_buckets_kernel<<<1, 1024, 0, stream>>>(tot, bucketbase, row_ptr);
    scatter_kernel     <<<NCHUNK, 1024, 0, stream>>>(edge_row, edge_col, edge_val,
                                                     bucketbase, Pt, tmp);
    bucket_sort_kernel <<<NBKT, 512, 0, stream>>>(bucketbase, tmp, row_ptr, edges);
    cvt_kernel         <<<(NN * DD / 2 + 255) / 256, 256, 0, stream>>>(
                         (const float2*)x, hb0);

    dim3 sp_grid((NN + 63) / 64);   // 1563 blocks, 4 lanes/row, 64 rows/block
    spmm_kernel<0><<<sp_grid, 256, 0, stream>>>(row_ptr, edges,
        (const uint4*)hb0, (uint4*)hb1, (const float4*)x, (float4*)out);
    spmm_kernel<1><<<sp_grid, 256, 0, stream>>>(row_ptr, edges,
        (const uint4*)hb1, (uint4*)hb0, (const float4*)x, (float4*)out);
    spmm_kernel<2><<<sp_grid, 256, 0, stream>>>(row_ptr, edges,
        (const uint4*)hb0, (uint4*)hb1, (const float4*)x, (float4*)out);
}

// Round 5
// 199.330 us; speedup vs baseline: 1.1678x; 1.1678x over previous
//
#include <hip/hip_runtime.h>

// LightGCN propagation on MI355X (gfx950).
//   h_{k+1}[r,:] = sum_{e: row[e]==r} val[e] * h_k[col[e],:]   D=32
//   out = (x + h1 + h2 + h3) / 4
//
// Round 14: R13 post-mortem -- col-sort bought spmm ~0 (total regressed by
// exactly bucket_sort's +37 us; 2.95M LDS bank conflicts from the serial
// insertion sort + contended single-copy cnt/cur atomics). Reverted.
// This round:
//  * bucket_sort v2: per-wave privatized counters cntw[8][128] and cursors
//    curw[8][128] -> LDS atomics are wave-local (near-zero same-address
//    serialization); LDS staging + coalesced writeback kept.
//  * spmm degree-equalized waves: bucket_sort emits rowperm (rows sorted
//    by degree within each 64-row half). Each spmm wave then covers a
//    degree quantile: max-deg ~= mean-deg, cutting divergent tail slots
//    ~30% (Poisson-16: wave max 25 -> ~17.5). Writes stay inside the same
//    4KB window so full-line writeback is preserved.

#define NN 100000
#define NE 1600000
#define DD 32
#define CHUNK 4096
#define NCHUNK ((NE + CHUNK - 1) / CHUNK)   // 391
#define BROWS 128
#define NBKT ((NN + BROWS - 1) / BROWS)     // 782
#define LDSE 3072                           // LDS staging cap in bucket_sort

__device__ __forceinline__ unsigned f2bf(float f) {
    unsigned u = __float_as_uint(f);
    return (u + 0x7fffu + ((u >> 16) & 1u)) >> 16;   // RNE
}

// ---- pass 1: per-chunk bucket histogram matrix H[c][b] (coalesced) -------

__global__ __launch_bounds__(1024) void hist_kernel(
    const int* __restrict__ row, int* __restrict__ H)
{
    __shared__ int cnt[NBKT];
    const int tid = threadIdx.x;
    const int start = blockIdx.x * CHUNK;
    const int n = min(CHUNK, NE - start);
    for (int k = tid; k < NBKT; k += 1024) cnt[k] = 0;
    __syncthreads();
    const int j = tid * 4;                       // 4 edges per thread
    if (j + 3 < n) {
        int4 r4 = *(const int4*)(row + start + j);
        atomicAdd(&cnt[r4.x >> 7], 1);
        atomicAdd(&cnt[r4.y >> 7], 1);
        atomicAdd(&cnt[r4.z >> 7], 1);
        atomicAdd(&cnt[r4.w >> 7], 1);
    } else {
        for (int k = j; k < n; k++) atomicAdd(&cnt[row[start + k] >> 7], 1);
    }
    __syncthreads();
    int* Hrow = H + (size_t)blockIdx.x * NBKT;
    for (int k = tid; k < NBKT; k += 1024) Hrow[k] = cnt[k];   // coalesced
}

// ---- pass 2a: wave-parallel per-bucket scan over chunks ------------------

__global__ __launch_bounds__(1024) void scan_tr_kernel(
    const int* __restrict__ H, int* __restrict__ Pt, int* __restrict__ tot)
{
    const int b = blockIdx.x * 16 + (threadIdx.x >> 6);
    if (b >= NBKT) return;
    const int lane = threadIdx.x & 63;
    int run = 0;
    #pragma unroll
    for (int c0 = 0; c0 < NCHUNK; c0 += 64) {
        int c = c0 + lane;
        int v = (c < NCHUNK) ? H[(size_t)c * NBKT + b] : 0;
        int x = v;
        #pragma unroll
        for (int off = 1; off < 64; off <<= 1) {
            int y = __shfl_up(x, off, 64);
            if (lane >= off) x += y;
        }
        if (c < NCHUNK) Pt[(size_t)b * NCHUNK + c] = run + x - v;  // exclusive
        run += __shfl(x, 63, 64);                 // wave total
    }
    if (lane == 0) tot[b] = run;
}

// ---- pass 2b: exclusive scan of 782 bucket totals ------------------------

__global__ __launch_bounds__(1024) void scan_buckets_kernel(
    const int* __restrict__ tot, int* __restrict__ bucketbase,
    int* __restrict__ row_ptr)
{
    const int tid = threadIdx.x;
    int v = (tid < NBKT) ? tot[tid] : 0;
    int lane = tid & 63, w = tid >> 6;          // 16 waves
    int x = v;
    #pragma unroll
    for (int off = 1; off < 64; off <<= 1) {
        int y = __shfl_up(x, off, 64);
        if (lane >= off) x += y;
    }
    __shared__ int wt[16];
    if (lane == 63) wt[w] = x;
    __syncthreads();
    if (w == 0 && lane < 16) {
        int y = wt[lane];
        #pragma unroll
        for (int off = 1; off < 16; off <<= 1) {
            int z = __shfl_up(y, off, 16);
            if ((lane & 15) >= off) y += z;
        }
        wt[lane] = y;                            // inclusive wave totals
    }
    __syncthreads();
    int wo = (w > 0) ? wt[w - 1] : 0;
    int excl = x + wo - v;
    if (tid < NBKT) bucketbase[tid] = excl;
    if (tid == NBKT) { bucketbase[NBKT] = NE; row_ptr[NN] = NE; }
}

// ---- pass 3: multisplit scatter, deterministic dest, LDS-staged stores ---
// record: ((row & 127) << 17) | col   (col < 2^17), val bits in .y

__global__ __launch_bounds__(1024) void scatter_kernel(
    const int* __restrict__ row, const int* __restrict__ col,
    const float* __restrict__ val, const int* __restrict__ bucketbase,
    const int* __restrict__ Pt, int2* __restrict__ tmp)
{
    __shared__ int cnt[NBKT];      // 3.1 KB
    __shared__ int lbase[NBKT];    // 3.1 KB  chunk-local exclusive scan
    __shared__ int gofs[NBKT];     // 3.1 KB  global base per bucket
    __shared__ int wt[16];
    __shared__ int2 recs[CHUNK];   // 32 KB   records in bucket order
    __shared__ int dest[CHUNK];    // 16 KB   global dst per sorted position
    const int tid = threadIdx.x;
    const int start = blockIdx.x * CHUNK;
    const int n = min(CHUNK, NE - start);
    for (int k = tid; k < NBKT; k += 1024) cnt[k] = 0;
    __syncthreads();

    int rrow[CHUNK / 1024], rcol[CHUNK / 1024], rank[CHUNK / 1024];
    float rval[CHUNK / 1024];
    #pragma unroll
    for (int k = 0; k < CHUNK / 1024; k++) {
        int j = k * 1024 + tid;
        if (j < n) {
            int r = row[start + j];
            rrow[k] = r;
            rcol[k] = col[start + j];
            rval[k] = val[start + j];
            rank[k] = atomicAdd(&cnt[r >> 7], 1);
        } else {
            rrow[k] = -1;
        }
    }
    __syncthreads();

    // block-level exclusive scan of cnt -> lbase; deterministic gofs
    int v = (tid < NBKT) ? cnt[tid] : 0;
    {
        int lane = tid & 63, w = tid >> 6;
        int x = v;
        #pragma unroll
        for (int off = 1; off < 64; off <<= 1) {
            int y = __shfl_up(x, off, 64);
            if (lane >= off) x += y;
        }
        if (lane == 63) wt[w] = x;
        __syncthreads();
        if (w == 0 && lane < 16) {
            int y = wt[lane];
            #pragma unroll
            for (int off = 1; off < 16; off <<= 1) {
                int z = __shfl_up(y, off, 16);
                if ((lane & 15) >= off) y += z;
            }
            wt[lane] = y;
        }
        __syncthreads();
        int excl = x + ((w > 0) ? wt[w - 1] : 0) - v;
        if (tid < NBKT) {
            lbase[tid] = excl;
            gofs[tid] = bucketbase[tid] + Pt[(size_t)tid * NCHUNK + blockIdx.x];
        }
    }
    __syncthreads();

    #pragma unroll
    for (int k = 0; k < CHUNK / 1024; k++) {
        if (rrow[k] >= 0) {
            int b = rrow[k] >> 7;
            int p = lbase[b] + rank[k];
            recs[p] = make_int2(((rrow[k] & 127) << 17) | rcol[k],
                                __float_as_int(rval[k]));
            dest[p] = gofs[b] + rank[k];
        }
    }
    __syncthreads();

    for (int p = tid; p < n; p += 1024)        // run-contiguous stores
        tmp[dest[p]] = recs[p];
}

// ---- pass 4: per-bucket row sort (wave-privatized) + degree perm ---------
// cntw/curw are per-wave -> LDS atomics are wave-local, no cross-wave
// same-address serialization. Also emits rowperm: rows sorted by degree
// within each 64-row half (degree-equalized spmm waves).

__global__ __launch_bounds__(512) void bucket_sort_kernel(
    const int* __restrict__ bucketbase, const int2* __restrict__ tmp,
    int* __restrict__ row_ptr, int2* __restrict__ edges,
    int* __restrict__ rowperm)
{
    __shared__ int cntw[8][BROWS];   // 4 KB  per-wave counts
    __shared__ int curw[8][BROWS];   // 4 KB  per-wave cursors
    __shared__ int base[BROWS];
    __shared__ int degsh[BROWS];
    __shared__ int wt2[2];
    __shared__ int2 ed[LDSE];        // 24 KB staging
    const int tid = threadIdx.x;
    const int w   = tid >> 6;        // wave id 0..7
    const int b   = blockIdx.x;
    const int s   = bucketbase[b];
    const int e   = bucketbase[b + 1];
    const int tot = e - s;

    for (int k = tid; k < 8 * BROWS; k += 512) (&cntw[0][0])[k] = 0;
    __syncthreads();

    int2 rc[6];
    #pragma unroll
    for (int k = 0; k < 6; k++) {
        int j = s + k * 512 + tid;
        rc[k] = (j < e && j < s + LDSE) ? tmp[j] : make_int2(-1, 0);
        if (rc[k].x >= 0) atomicAdd(&cntw[w][rc[k].x >> 17], 1);
    }
    if (tot > LDSE)                                        // fallback count
        for (int j = s + LDSE + tid; j < e; j += 512)
            atomicAdd(&cntw[w][tmp[j].x >> 17], 1);
    __syncthreads();

    // deg per row, block-exclusive scan -> base
    int v = 0, x = 0;
    if (tid < BROWS) {
        int d = 0;
        #pragma unroll
        for (int ww = 0; ww < 8; ww++) d += cntw[ww][tid];
        degsh[tid] = d;
        v = d;
        int lane = tid & 63;
        x = v;
        #pragma unroll
        for (int off = 1; off < 64; off <<= 1) {
            int y = __shfl_up(x, off, 64);
            if (lane >= off) x += y;
        }
        if (lane == 63) wt2[tid >> 6] = x;
    }
    __syncthreads();
    if (tid < BROWS) {
        int excl = x + ((tid >> 6) ? wt2[0] : 0) - v;
        base[tid] = excl;
        int r = b * BROWS + tid;
        if (r < NN) row_ptr[r] = s + excl;
        // per-wave cursors: running sum across waves
        int run = excl;
        #pragma unroll
        for (int ww = 0; ww < 8; ww++) { curw[ww][tid] = run; run += cntw[ww][tid]; }
        // degree-rank perm within each 64-row half
        int half0 = tid & 64;
        int d = degsh[tid];
        int rank = 0;
        #pragma unroll 8
        for (int j2 = 0; j2 < 64; j2++) {
            int dj = degsh[half0 + j2];
            rank += (dj < d) || (dj == d && (half0 + j2) < tid);
        }
        rowperm[b * BROWS + half0 + rank] = b * BROWS + tid;
    }
    __syncthreads();

    if (tot <= LDSE) {
        #pragma unroll
        for (int k = 0; k < 6; k++) {
            if (rc[k].x >= 0) {
                int pos = atomicAdd(&curw[w][rc[k].x >> 17], 1);
                ed[pos] = make_int2(rc[k].x & 0x1FFFF, rc[k].y);
            }
        }
        __syncthreads();
        for (int k = tid; k < tot; k += 512)     // coalesced write-back
            edges[s + k] = ed[k];
    } else {
        // fallback (statistically unreachable: bucket > 3072)
        #pragma unroll
        for (int k = 0; k < 6; k++) {
            if (rc[k].x >= 0) {
                int pos = atomicAdd(&curw[w][rc[k].x >> 17], 1);
                edges[s + pos] = make_int2(rc[k].x & 0x1FFFF, rc[k].y);
            }
        }
        for (int j = s + LDSE + tid; j < e; j += 512) {
            int2 rec = tmp[j];
            int pos = atomicAdd(&curw[w][rec.x >> 17], 1);
            edges[s + pos] = make_int2(rec.x & 0x1FFFF, rec.y);
        }
    }
}

// ---- x -> bf16 table (feat 2k in low half, 2k+1 in high half) ------------

__global__ __launch_bounds__(256) void cvt_kernel(
    const float2* __restrict__ xin2, unsigned* __restrict__ hb)
{
    int j = blockIdx.x * 256 + threadIdx.x;      // word index, NN*DD/2 words
    if (j >= NN * DD / 2) return;
    float2 f = xin2[j];
    hb[j] = f2bf(f.x) | (f2bf(f.y) << 16);
}

// ---- SpMM: 4-lane group per row (degree-permuted), bf16 gather -----------
// Lane t in [0,4) owns feats [8t, 8t+8) = one uint4 of the bf16 row.
// rowperm groups similar-degree rows into each wave -> max-deg ~ mean-deg,
// minimal divergent tail. 8 gathers in flight.
// MODE 0: houtb = bf16(A x)  ; out  = x + A x
// MODE 1: houtb = bf16(A h)  ; out += A h
// MODE 2: out = (out + A h) * 0.25

template <int MODE>
__global__ __launch_bounds__(256) void spmm_kernel(
    const int* __restrict__ row_ptr, const int2* __restrict__ edges,
    const int* __restrict__ rowperm,
    const uint4* __restrict__ hb4,               // bf16 table, 4 uint4/row
    uint4* __restrict__ houtb4,                  // next bf16 table
    const float4* __restrict__ xin4, float4* __restrict__ out4)
{
    const int g0 = blockIdx.x * 64 + (threadIdx.x >> 2);  // slot
    const int g = rowperm[g0];                            // row
    if (g >= NN) return;
    const int t = threadIdx.x & 3;
    const int s = row_ptr[g];
    const int e = row_ptr[g + 1];

    float acc[8] = {0.f, 0.f, 0.f, 0.f, 0.f, 0.f, 0.f, 0.f};

#define ACC8(W, V)                                                         \
    do {                                                                   \
        acc[0] += (V) * __uint_as_float((W).x << 16);                      \
        acc[1] += (V) * __uint_as_float((W).x & 0xffff0000u);              \
        acc[2] += (V) * __uint_as_float((W).y << 16);                      \
        acc[3] += (V) * __uint_as_float((W).y & 0xffff0000u);              \
        acc[4] += (V) * __uint_as_float((W).z << 16);                      \
        acc[5] += (V) * __uint_as_float((W).z & 0xffff0000u);              \
        acc[6] += (V) * __uint_as_float((W).w << 16);                      \
        acc[7] += (V) * __uint_as_float((W).w & 0xffff0000u);              \
    } while (0)

    int i = s;
    for (; i + 8 <= e; i += 8) {                 // 8 gathers in flight
        int2 a0 = edges[i];
        int2 a1 = edges[i + 1];
        int2 a2 = edges[i + 2];
        int2 a3 = edges[i + 3];
        int2 a4 = edges[i + 4];
        int2 a5 = edges[i + 5];
        int2 a6 = edges[i + 6];
        int2 a7 = edges[i + 7];
        uint4 w0 = hb4[a0.x * 4 + t];
        uint4 w1 = hb4[a1.x * 4 + t];
        uint4 w2 = hb4[a2.x * 4 + t];
        uint4 w3 = hb4[a3.x * 4 + t];
        uint4 w4 = hb4[a4.x * 4 + t];
        uint4 w5 = hb4[a5.x * 4 + t];
        uint4 w6 = hb4[a6.x * 4 + t];
        uint4 w7 = hb4[a7.x * 4 + t];
        ACC8(w0, __int_as_float(a0.y)); ACC8(w1, __int_as_float(a1.y));
        ACC8(w2, __int_as_float(a2.y)); ACC8(w3, __int_as_float(a3.y));
        ACC8(w4, __int_as_float(a4.y)); ACC8(w5, __int_as_float(a5.y));
        ACC8(w6, __int_as_float(a6.y)); ACC8(w7, __int_as_float(a7.y));
    }
    for (; i + 4 <= e; i += 4) {
        int2 a0 = edges[i];
        int2 a1 = edges[i + 1];
        int2 a2 = edges[i + 2];
        int2 a3 = edges[i + 3];
        uint4 w0 = hb4[a0.x * 4 + t];
        uint4 w1 = hb4[a1.x * 4 + t];
        uint4 w2 = hb4[a2.x * 4 + t];
        uint4 w3 = hb4[a3.x * 4 + t];
        ACC8(w0, __int_as_float(a0.y)); ACC8(w1, __int_as_float(a1.y));
        ACC8(w2, __int_as_float(a2.y)); ACC8(w3, __int_as_float(a3.y));
    }
    for (; i < e; ++i) {
        int2 a0 = edges[i];
        uint4 w0 = hb4[a0.x * 4 + t];
        ACC8(w0, __int_as_float(a0.y));
    }
#undef ACC8

    // epilogue: lane owns feats [8t, 8t+8)
    if (MODE == 0 || MODE == 1) {
        uint4 p;
        p.x = f2bf(acc[0]) | (f2bf(acc[1]) << 16);
        p.y = f2bf(acc[2]) | (f2bf(acc[3]) << 16);
        p.z = f2bf(acc[4]) | (f2bf(acc[5]) << 16);
        p.w = f2bf(acc[6]) | (f2bf(acc[7]) << 16);
        houtb4[g * 4 + t] = p;
    }
    const int o = g * 8 + t * 2;                 // two float4s per lane
    float4 lo, hi;
    if (MODE == 0) {
        float4 x0 = xin4[o], x1 = xin4[o + 1];
        lo = make_float4(x0.x + acc[0], x0.y + acc[1], x0.z + acc[2], x0.w + acc[3]);
        hi = make_float4(x1.x + acc[4], x1.y + acc[5], x1.z + acc[6], x1.w + acc[7]);
    } else if (MODE == 1) {
        float4 o0 = out4[o], o1 = out4[o + 1];
        lo = make_float4(o0.x + acc[0], o0.y + acc[1], o0.z + acc[2], o0.w + acc[3]);
        hi = make_float4(o1.x + acc[4], o1.y + acc[5], o1.z + acc[6], o1.w + acc[7]);
    } else {
        float4 o0 = out4[o], o1 = out4[o + 1];
        lo = make_float4((o0.x + acc[0]) * 0.25f, (o0.y + acc[1]) * 0.25f,
                         (o0.z + acc[2]) * 0.25f, (o0.w + acc[3]) * 0.25f);
        hi = make_float4((o1.x + acc[4]) * 0.25f, (o1.y + acc[5]) * 0.25f,
                         (o1.z + acc[6]) * 0.25f, (o1.w + acc[7]) * 0.25f);
    }
    out4[o] = lo;
    out4[o + 1] = hi;
}

// ---- launch ---------------------------------------------------------------

extern "C" void kernel_launch(void* const* d_in, const int* in_sizes, int n_in,
                              void* d_out, int out_size, void* d_ws, size_t ws_size,
                              hipStream_t stream) {
    const int*   edge_row = (const int*)d_in[0];
    const int*   edge_col = (const int*)d_in[1];
    const float* edge_val = (const float*)d_in[2];
    const float* x        = (const float*)d_in[3];
    float* out = (float*)d_out;

    char* ws = (char*)d_ws;
    int*  H          = (int*)ws;   ws += (((size_t)NCHUNK * NBKT * 4) + 511) & ~511ull; // 1.22 MB
    int*  Pt         = (int*)ws;   ws += (((size_t)NBKT * NCHUNK * 4) + 511) & ~511ull; // 1.22 MB
    int*  tot        = (int*)ws;   ws += 4096;
    int*  bucketbase = (int*)ws;   ws += 4096;
    int*  row_ptr    = (int*)ws;   ws += ((size_t)(NN + 1) * 4 + 511) & ~511ull;
    int*  rowperm    = (int*)ws;   ws += (((size_t)NBKT * BROWS * 4) + 511) & ~511ull;  // 400 KB
    int2* tmp        = (int2*)ws;  ws += (size_t)NE * 8 + 64;   // 12.8 MB
    int2* edges      = (int2*)ws;  ws += (size_t)NE * 8 + 64;   // 12.8 MB
    unsigned* hb0    = (unsigned*)ws;  ws += (size_t)NN * DD * 2;  // 6.4 MB bf16
    unsigned* hb1    = (unsigned*)ws;  ws += (size_t)NN * DD * 2;  // 6.4 MB bf16

    hist_kernel        <<<NCHUNK, 1024, 0, stream>>>(edge_row, H);
    scan_tr_kernel     <<<(NBKT + 15) / 16, 1024, 0, stream>>>(H, Pt, tot);
    scan_buckets_kernel<<<1, 1024, 0, stream>>>(tot, bucketbase, row_ptr);
    scatter_kernel     <<<NCHUNK, 1024, 0, stream>>>(edge_row, edge_col, edge_val,
                                                     bucketbase, Pt, tmp);
    bucket_sort_kernel <<<NBKT, 512, 0, stream>>>(bucketbase, tmp, row_ptr, edges,
                                                  rowperm);
    cvt_kernel         <<<(NN * DD / 2 + 255) / 256, 256, 0, stream>>>(
                         (const float2*)x, hb0);

    dim3 sp_grid((NN + 63) / 64);   // 1563 blocks, 4 lanes/row, 64 rows/block
    spmm_kernel<0><<<sp_grid, 256, 0, stream>>>(row_ptr, edges, rowperm,
        (const uint4*)hb0, (uint4*)hb1, (const float4*)x, (float4*)out);
    spmm_kernel<1><<<sp_grid, 256, 0, stream>>>(row_ptr, edges, rowperm,
        (const uint4*)hb1, (uint4*)hb0, (const float4*)x, (float4*)out);
    spmm_kernel<2><<<sp_grid, 256, 0, stream>>>(row_ptr, edges, rowperm,
        (const uint4*)hb0, (uint4*)hb1, (const float4*)x, (float4*)out);
}